// Round 11
// baseline (1336.365 us; speedup 1.0000x reference)
//
#include <hip/hip_runtime.h>
#include <hip/hip_fp16.h>

// Workspace: 384 MiB.
//   A [0,128M):   q_h (64M) -> k_h/k_l -> qk (f32, 128M)
//   D [128,256M): qT_h/qT_l -> P (64M) + vT (64M)
//   E [256,384M): kk_h (64M) + val_h (64M)
// d_out scratch (dead before final GEMM): wq_h/l, wk_h, wv_h

using half8_t = __attribute__((ext_vector_type(8))) _Float16;
using f32x4   = __attribute__((ext_vector_type(4))) float;

static constexpr int NB = 8;
static constexpr int Sd = 2048;
static constexpr long MAT = (long)Sd * Sd;

__device__ __forceinline__ void gload16(const _Float16* g, _Float16* l) {
  __builtin_amdgcn_global_load_lds(
      (const __attribute__((address_space(1))) void*)g,
      (__attribute__((address_space(3))) void*)l, 16, 0, 0);
}
__device__ __forceinline__ void barrier_() { asm volatile("s_barrier" ::: "memory"); }
__device__ __forceinline__ void lgkm0_()   { asm volatile("s_waitcnt lgkmcnt(0)" ::: "memory"); }
#define VMCNT(n) asm volatile("s_waitcnt vmcnt(" #n ")" ::: "memory")
#define SCHEDB() __builtin_amdgcn_sched_barrier(0)

// ---------------------------------------------------------------------------
// presplit: f32 -> fp16 hi (+ residual lo if SPLIT), scaled.
// ---------------------------------------------------------------------------
template<bool SPLIT>
__global__ __launch_bounds__(256) void presplit(const float* __restrict__ in,
    _Float16* __restrict__ h, _Float16* __restrict__ l, long n8, float scl)
{
  long i = (long)blockIdx.x * 256 + threadIdx.x;
  const long stride = (long)gridDim.x * 256;
  for (; i < n8; i += stride) {
    const f32x4* p = (const f32x4*)(in + i * 8);
    f32x4 a = p[0], b = p[1];
    half8_t hh, ll;
#pragma unroll
    for (int j = 0; j < 4; j++) {
      float x = a[j] * scl; _Float16 hv = (_Float16)x;
      hh[j] = hv; if constexpr (SPLIT) ll[j] = (_Float16)(x - (float)hv);
      float y = b[j] * scl; _Float16 hw = (_Float16)y;
      hh[4 + j] = hw; if constexpr (SPLIT) ll[4 + j] = (_Float16)(y - (float)hw);
    }
    *(half8_t*)(h + i * 8) = hh;
    if constexpr (SPLIT) *(half8_t*)(l + i * 8) = ll;
  }
}

// ---------------------------------------------------------------------------
// gemm11 (B^T form): C[i][j] = cscale * sum_k A[i][k]*B[j][k] (+ bias)
// OCCUPANCY-FIRST variant: 128x256 tile, 8 waves (2x4 of 64x64 each),
// acc 4x4 f32x4 = 64 regs/wave -> <=128 unified regs -> launch_bounds(512,4)
// -> with 48KB LDS: 2 blocks/CU = 16 waves/CU = 4 waves/SIMD (vs 2 all prior
// rounds). Ring-2 of K-32 units; guide-verified minimal 2-phase schedule:
//   {stage(u+1) -> 8 ds_read(u) -> lgkm0 -> setprio+16 MFMA -> vmcnt(0) ->
//    barrier}  — per-phase drains hidden by the co-resident block (m114).
// WAR: stage(u+1) writes slot u^1 whose readers drained at lgkm0 before
// mfma(u-1), pre-barrier. RAW: vmcnt(0)+barrier publishes stage(u+1).
// A LDS (64B rows): slot = k8 ^ ((row>>1)&3)  — throughput-conflict-free.
// B LDS: r10's measured-0-conflict involution, verbatim.
// NSEG: 1 plain (K=2048); 2 = K-concat split [Ah|Al]x[Bh|Bh] (K=4096).
// BIAS: 0 none, 1 bias[n], 2 bias[m].
// OUT: 0 f32, 1 fp16, 2 split fp16 (x16), 3 fp16 hi-only (x16).
// ---------------------------------------------------------------------------
template<int NSEG, int BIAS, int OUT>
__global__ __launch_bounds__(512, 4) void gemm11(
    const _Float16* __restrict__ Ah, const _Float16* __restrict__ Al, long sA,
    const _Float16* __restrict__ Bh, long sB,
    const float* __restrict__ bias, float cscale,
    void* __restrict__ Cp, void* __restrict__ Clp, long sC)
{
  constexpr int H = NSEG * 64;      // K-32 phases
  __shared__ __align__(16) _Float16 LA[2][4096];   // 2 x 8KB  (128x32)
  __shared__ __align__(16) _Float16 LB[2][8192];   // 2 x 16KB (256x32)

  const int t = threadIdx.x, w = t >> 6, l = t & 63;

  // XCD swizzle: 1024 wgs -> 128 consecutive per XCD (one batch per XCD)
  const int wg = blockIdx.x;
  const int swz = (wg & 7) * 128 + (wg >> 3);
  const int bz = swz >> 7, rem = swz & 127;
  const int by = rem >> 3, bx = rem & 7;   // 16 row-tiles x 8 col-tiles

  const _Float16* PAh = Ah + (size_t)bz * sA + (size_t)(by * 128) * Sd;
  const _Float16* PBh = Bh + (size_t)bz * sB + (size_t)(bx * 256) * Sd;
  const _Float16* PAl = (NSEG == 2)
      ? Al + (size_t)bz * sA + (size_t)(by * 128) * Sd : PAh;

  // A staging: thread t -> row t>>2, k8-slot (t&3)^((t>>3)&3); dest slot t.
  const size_t srcA_off = (size_t)(t >> 2) * Sd
                        + (size_t)(((t & 3) ^ ((t >> 3) & 3)) * 8);
  // B staging: r10 verbatim (slot S covers row 2*(S>>3)+(S&1)).
  const int s7 = t & 7;
  const size_t srcB_off = (size_t)(2 * (t >> 3) + (s7 & 1)) * Sd
                        + (size_t)(((s7 >> 1) ^ ((t >> 3) & 3)) * 8);
  const int du0 = w * 512;   // elems; + HW lane*8

  // read geometry
  const int wm = (w >> 2) * 64, wn = (w & 3) * 64;
  const int lm = l & 15, lkr = l >> 4;
  const int aoff = wm * 64 + lm * 64 + ((lkr ^ ((lm >> 1) & 3)) * 16);
  const int sprime = ((lkr ^ ((lm >> 1) & 3)) << 1) | (lm & 1);
  const int boff = (wn >> 1) * 128 + (lm >> 1) * 128 + sprime * 16;

  auto srcAh = [&](int hp) -> const _Float16* {
    if constexpr (NSEG == 2) return (hp >> 6) ? PAl : PAh;
    return PAh;
  };
  auto koOf = [&](int hp) -> int {
    if constexpr (NSEG == 2) return (hp & 63) * 32;
    return hp * 32;
  };
  auto stageP = [&](int hp) {   // 3 global_load_lds: A(1) + B(2)
    const int u = hp & 1;
    const _Float16* a = srcAh(hp) + koOf(hp);
    const _Float16* b = PBh + koOf(hp);
    gload16(a + srcA_off, LA[u] + du0);
    gload16(b + srcB_off, LB[u] + du0);
    gload16(b + srcB_off + (size_t)128 * Sd, LB[u] + du0 + 4096);
  };

  f32x4 acc[4][4] = {};
  half8_t fa[4], fb[4];

  // ---- prologue
  stageP(0);
  VMCNT(0);
  barrier_();

  for (int u = 0; u < H; ++u) {
    if (u + 1 < H) stageP(u + 1);
    const int s = u & 1;
#pragma unroll
    for (int f = 0; f < 4; f++)
      fa[f] = *(const half8_t*)((const char*)LA[s] + aoff + f * 1024);
#pragma unroll
    for (int n = 0; n < 4; n++)
      fb[n] = *(const half8_t*)((const char*)LB[s] + boff + n * 1024);
    lgkm0_(); SCHEDB();
    __builtin_amdgcn_s_setprio(1);
#pragma unroll
    for (int fm = 0; fm < 4; fm++)
#pragma unroll
      for (int fn = 0; fn < 4; fn++)
        acc[fm][fn] = __builtin_amdgcn_mfma_f32_16x16x32_f16(
            fa[fm], fb[fn], acc[fm][fn], 0, 0, 0);
    __builtin_amdgcn_s_setprio(0);
    if (u + 1 < H) { VMCNT(0); barrier_(); }
  }

  // ---- epilogue: C/D layout col = lane&15, row = (lane>>4)*4 + reg
  const int row_base = by * 128 + wm + (lkr << 2);
  const int col_base = bx * 256 + wn + lm;
#pragma unroll
  for (int fm = 0; fm < 4; fm++)
#pragma unroll
    for (int fn = 0; fn < 4; fn++) {
      const int n = col_base + fn * 16;
      float bcol = 0.f;
      if constexpr (BIAS == 1) bcol = bias[n];
#pragma unroll
      for (int r = 0; r < 4; r++) {
        const int m = row_base + fm * 16 + r;
        float v = acc[fm][fn][r] * cscale;
        if constexpr (BIAS == 1) v += bcol;
        if constexpr (BIAS == 2) v += bias[m];
        const size_t ci = (size_t)bz * sC + (size_t)m * Sd + n;
        if constexpr (OUT == 0) ((float*)Cp)[ci] = v;
        else if constexpr (OUT == 1) ((_Float16*)Cp)[ci] = (_Float16)v;
        else if constexpr (OUT == 3) ((_Float16*)Cp)[ci] = (_Float16)(v * 16.0f);
        else {
          float sv = v * 16.0f;
          _Float16 hv = (_Float16)sv;
          ((_Float16*)Cp)[ci]  = hv;
          ((_Float16*)Clp)[ci] = (_Float16)(sv - (float)hv);
        }
      }
    }
}

// ---------------------------------------------------------------------------
// Row softmax: one 256-thread block per row of 2048 f32 -> fp16 probs.
// ---------------------------------------------------------------------------
__global__ __launch_bounds__(256) void softmax_rows(const float* __restrict__ X,
                                                    _Float16* __restrict__ P)
{
  __shared__ float red[4];
  const size_t row = blockIdx.x;
  const float* x = X + row * Sd;
  _Float16* p = P + row * Sd;
  const int t = threadIdx.x;
  float v[8];
  float mx = -1e30f;
#pragma unroll
  for (int i = 0; i < 8; i++) { v[i] = x[t + 256 * i]; mx = fmaxf(mx, v[i]); }
#pragma unroll
  for (int o = 32; o > 0; o >>= 1) mx = fmaxf(mx, __shfl_xor(mx, o, 64));
  if ((t & 63) == 0) red[t >> 6] = mx;
  __syncthreads();
  mx = fmaxf(fmaxf(red[0], red[1]), fmaxf(red[2], red[3]));
  __syncthreads();
  float s = 0.f;
#pragma unroll
  for (int i = 0; i < 8; i++) { v[i] = __expf(v[i] - mx); s += v[i]; }
#pragma unroll
  for (int o = 32; o > 0; o >>= 1) s += __shfl_xor(s, o, 64);
  if ((t & 63) == 0) red[t >> 6] = s;
  __syncthreads();
  s = red[0] + red[1] + red[2] + red[3];
  float inv = 1.f / s;
#pragma unroll
  for (int i = 0; i < 8; i++) p[t + 256 * i] = (_Float16)(v[i] * inv);
}

// ---------------------------------------------------------------------------
extern "C" void kernel_launch(void* const* d_in, const int* in_sizes, int n_in,
                              void* d_out, int out_size, void* d_ws, size_t ws_size,
                              hipStream_t stream)
{
  const float* query = (const float*)d_in[0];
  const float* key_  = (const float*)d_in[1];
  const float* value = (const float*)d_in[2];
  const float* Wq = (const float*)d_in[3];
  const float* bq = (const float*)d_in[4];
  const float* Wk = (const float*)d_in[5];
  const float* bk = (const float*)d_in[6];
  const float* Wv = (const float*)d_in[7];
  const float* bv = (const float*)d_in[8];

  char* ws = (char*)d_ws;
  char* ob = (char*)d_out;
  const size_t M64 = (size_t)NB * MAT * 2;   // 64 MiB

  _Float16* q_h  = (_Float16*)(ws);                 // A[0,64)
  _Float16* k_h  = (_Float16*)(ws);                 // A[0,64) (q dead)
  _Float16* k_l  = (_Float16*)(ws + M64);           // A[64,128)
  float*    qk   = (float*)(ws);                    // A as f32 (k dead)
  _Float16* qT_h = (_Float16*)(ws + 2 * M64);       // D[128,192)
  _Float16* qT_l = (_Float16*)(ws + 3 * M64);       // D[192,256)
  _Float16* P    = qT_h;                            // after qT dead
  _Float16* vT   = qT_l;
  _Float16* kk_h = (_Float16*)(ws + 4 * M64);       // E[256,320)
  _Float16* val_h = (_Float16*)(ws + 5 * M64);      // E[320,384)

  _Float16* wq_h = (_Float16*)(ob);
  _Float16* wq_l = (_Float16*)(ob + (MAT * 2));
  _Float16* wk_h = (_Float16*)(ob + 2 * (MAT * 2));
  _Float16* wv_h = (_Float16*)(ob + 3 * (MAT * 2));
  float* out = (float*)d_out;

  dim3 blk256(256), blk512(512);
  dim3 gg(1024);   // 8 batches x 16x8 tiles of 128x256
  const long NQ8 = (long)NB * MAT / 8;
  const long NW8 = MAT / 8;

  // 1. presplit query (hi only, x16), Wq (hi+lo, x16)
  presplit<false><<<dim3(2048), blk256, 0, stream>>>(query, q_h, nullptr, NQ8, 16.f);
  presplit<true><<<dim3(2048), blk256, 0, stream>>>(Wq, wq_h, wq_l, NW8, 16.f);
  // 2. qT[e][s] = sum_d Wq[e][d]*query[s][d] + bq[e] (row bias), split out
  gemm11<2, 2, 2><<<gg, blk512, 0, stream>>>(wq_h, wq_l, 0, q_h, MAT,
                                             bq, 1.f / 256.f, qT_h, qT_l, MAT);
  // 3. presplit key_ (hi+lo, x16), Wk (hi only, x16)
  presplit<true><<<dim3(2048), blk256, 0, stream>>>(key_, k_h, k_l, NQ8, 16.f);
  presplit<false><<<dim3(2048), blk256, 0, stream>>>(Wk, wk_h, nullptr, NW8, 16.f);
  // 4. kk[s'][e] = sum_d key_[s'][d]*Wk[e][d] + bk[e] (col bias), hi-only out
  gemm11<2, 1, 3><<<gg, blk512, 0, stream>>>(k_h, k_l, MAT, wk_h, 0,
                                             bk, 1.f / 256.f, kk_h, nullptr, MAT);
  // 5. qk[e][s'] = sum_m qT[e][m]*kk[s'][m]  (f32 out)
  gemm11<2, 0, 0><<<gg, blk512, 0, stream>>>(qT_h, qT_l, MAT, kk_h, MAT,
                                             nullptr, 1.f / 256.f, qk, nullptr, MAT);
  // 6. P = row-softmax(qk), fp16
  softmax_rows<<<dim3(NB * Sd), blk256, 0, stream>>>(qk, P);
  // 7. presplit value (x1), Wv (x1)
  presplit<false><<<dim3(2048), blk256, 0, stream>>>(value, val_h, nullptr, NQ8, 1.f);
  presplit<false><<<dim3(2048), blk256, 0, stream>>>(Wv, wv_h, nullptr, NW8, 1.f);
  // 8. vT[d'][s'] = sum_d Wv[d'][d]*value[s'][d] + bv[d'] (row bias), fp16
  gemm11<1, 2, 1><<<gg, blk512, 0, stream>>>(wv_h, nullptr, 0, val_h, MAT,
                                             bv, 1.f, vT, nullptr, MAT);
  // 9. out[d'][e] = sum_s' vT[d'][s']*P[e][s']  (f32 -> d_out)
  gemm11<1, 0, 0><<<gg, blk512, 0, stream>>>(vT, nullptr, MAT, P, MAT,
                                             nullptr, 1.f, out, nullptr, MAT);
}